// Round 6
// baseline (309.278 us; speedup 1.0000x reference)
//
#include <hip/hip_runtime.h>
#include <hip/hip_cooperative_groups.h>
#include <math.h>

namespace cg = cooperative_groups;

#define BB 2
#define SS 512
#define DD 64
#define NC 32        // time chunks
#define CL 16        // SS/NC

// ---------------- Phase A: stats pass (wave per (b,t, quarter)) ----------------
// x read once at 16 B/lane. Produces partA[bt][q]=(s1,s2) and zbuf[bt][r]=sum_c x*lnw*dw.
__device__ __forceinline__ void phaseA_body(
    const float* __restrict__ x, const float* __restrict__ ln_w,
    const float* __restrict__ dt_w,
    float2* __restrict__ partA, float* __restrict__ zbuf,
    int gwA, int ln)
{
    const int bt = gwA >> 2;                 // 0..1023
    const int q  = gwA & 3;
    const float4* xp = (const float4*)(x + (size_t)bt * 4096 + q * 1024 + ln * 16);
    const float4* wp = (const float4*)(ln_w + q * 1024 + ln * 16);
    const float4* dp = (const float4*)(dt_w + (ln & 3) * 16);

    float s1 = 0.f, s2 = 0.f, z = 0.f;
    #pragma unroll
    for (int i = 0; i < 4; ++i) {
        float4 v = xp[i], w = wp[i], dv = dp[i];
        s1 += v.x + v.y + v.z + v.w;
        s2 += v.x*v.x + v.y*v.y + v.z*v.z + v.w*v.w;
        z  += v.x*w.x*dv.x + v.y*w.y*dv.y + v.z*w.z*dv.z + v.w*w.w*dv.w;
    }
    #pragma unroll
    for (int off = 32; off; off >>= 1) {
        s1 += __shfl_xor(s1, off);
        s2 += __shfl_xor(s2, off);
    }
    z += __shfl_xor(z, 1);
    z += __shfl_xor(z, 2);
    if (ln == 0) partA[gwA] = make_float2(s1, s2);
    if ((ln & 3) == 0) zbuf[bt * DD + (q * 16 + (ln >> 2))] = z;
}

// ---------------- Phase B: finalize stats, dt->decay, local chunk scan ----------------
// wave per (b, r, ch); lane = c. Re-reads x (L3-resident).
__device__ __forceinline__ void phaseB_body(
    const float* __restrict__ x, const float* __restrict__ log_A,
    const float* __restrict__ dt_b, const float* __restrict__ ln_w,
    const float* __restrict__ ln_b, const float* __restrict__ dt_w,
    const float2* __restrict__ partA, const float* __restrict__ zbuf,
    float2* __restrict__ statbuf, float* __restrict__ abuf,
    float* __restrict__ Fbuf, float* __restrict__ Pbuf,
    int gw, int c)
{
    const int ch = gw & (NC - 1);
    const int br = gw >> 5;
    const int b  = br >> 6, r = br & 63;
    const int t0 = ch * CL;

    const float lnw = ln_w[r * DD + c];
    const float lnb = ln_b[r * DD + c];
    const float dwc = dt_w[c];
    float w1 = lnw * dwc, b1 = lnb * dwc;
    #pragma unroll
    for (int off = 32; off; off >>= 1) {
        w1 += __shfl_xor(w1, off);
        b1 += __shfl_xor(b1, off);
    }
    const float Ar  = -expf(log_A[r]);
    const float dtb = dt_b[0];

    const size_t xbase = (((size_t)(b * SS + t0)) * DD + r) * DD + c;
    float state = 0.f, P = 1.f;
    #pragma unroll 4
    for (int t = 0; t < CL; ++t) {
        const int bt = b * SS + t0 + t;
        const float4* pa = (const float4*)(partA + bt * 4);
        float4 A0 = pa[0], A1 = pa[1];
        const float s1 = A0.x + A0.z + A1.x + A1.z;
        const float s2 = A0.y + A0.w + A1.y + A1.w;
        const float mu   = s1 * (1.0f / 4096.0f);
        const float var  = s2 * (1.0f / 4096.0f) - mu * mu;
        const float rstd = rsqrtf(var + 1e-5f);
        const float zr = zbuf[bt * DD + r];
        const float zz = fmaf(rstd, zr - mu * w1, b1) + dtb;
        const float dt = (zz > 20.f) ? zz : log1pf(expf(zz));   // softplus
        const float av = expf(dt * Ar);                         // decay in (0,1]
        const float xv = x[xbase + (size_t)t * DD * DD];
        const float xn = fmaf((xv - mu) * rstd, lnw, lnb);
        state = fmaf(av, state, xn);
        P *= av;
        if (c == 0) abuf[bt * DD + r] = av;
        if (c == 0 && r == 0) statbuf[bt] = make_float2(mu, rstd);
    }
    Fbuf[(size_t)gw * DD + c] = state;
    if (c == 0) Pbuf[gw] = P;
}

// ---------------- Phase C: cross-chunk carry + final scan + output ----------------
__device__ __forceinline__ void phaseC_body(
    const float* __restrict__ x, const float* __restrict__ ln_w,
    const float* __restrict__ ln_b,
    const float2* __restrict__ statbuf, const float* __restrict__ abuf,
    const float* __restrict__ Fbuf, const float* __restrict__ Pbuf,
    float* __restrict__ out, int gw, int c)
{
    const int ch = gw & (NC - 1);
    const int br = gw >> 5;
    const int b  = br >> 6, r = br & 63;
    const int t0 = ch * CL;
    const float lnw = ln_w[r * DD + c];
    const float lnb = ln_b[r * DD + c];

    float carry = 0.f;
    for (int vb = 0; vb < NC; vb += 8) {
        float f[8], p[8];
        #pragma unroll
        for (int i = 0; i < 8; ++i) {
            f[i] = Fbuf[(size_t)(br * NC + vb + i) * DD + c];
            p[i] = Pbuf[br * NC + vb + i];
        }
        #pragma unroll
        for (int i = 0; i < 8; ++i) {
            const int v = vb + i;
            carry = fmaf((v < ch) ? p[i] : 1.f, carry, (v < ch) ? f[i] : 0.f);
        }
    }

    const size_t xbase = (((size_t)(b * SS + t0)) * DD + r) * DD + c;
    float st = carry;
    #pragma unroll 4
    for (int t = 0; t < CL; ++t) {
        const int bt = b * SS + t0 + t;
        const float2 ms = statbuf[bt];
        const float av = abuf[bt * DD + r];
        const float xv = x[xbase + (size_t)t * DD * DD];
        const float xn = fmaf((xv - ms.x) * ms.y, lnw, lnb);
        st = fmaf(av, st, xn);
        out[xbase + (size_t)t * DD * DD] = st + xv;
    }
}

// ---------------- fused cooperative kernel ----------------
__global__ __launch_bounds__(256) void fused_all(
    const float* __restrict__ x, const float* __restrict__ log_A,
    const float* __restrict__ dt_w, const float* __restrict__ dt_b,
    const float* __restrict__ ln_w, const float* __restrict__ ln_b,
    float* __restrict__ out,
    float2* __restrict__ partA, float* __restrict__ zbuf,
    float2* __restrict__ statbuf, float* __restrict__ abuf,
    float* __restrict__ Fbuf, float* __restrict__ Pbuf)
{
    const int wv = threadIdx.x >> 6, ln = threadIdx.x & 63;
    const int gw = blockIdx.x * 4 + wv;
    phaseA_body(x, ln_w, dt_w, partA, zbuf, gw, ln);
    cg::this_grid().sync();
    phaseB_body(x, log_A, dt_b, ln_w, ln_b, dt_w, partA, zbuf,
                statbuf, abuf, Fbuf, Pbuf, gw, ln);
    cg::this_grid().sync();
    phaseC_body(x, ln_w, ln_b, statbuf, abuf, Fbuf, Pbuf, out, gw, ln);
}

// ---------------- fallback plain kernels ----------------
__global__ __launch_bounds__(256) void kA(
    const float* __restrict__ x, const float* __restrict__ ln_w,
    const float* __restrict__ dt_w,
    float2* __restrict__ partA, float* __restrict__ zbuf)
{
    phaseA_body(x, ln_w, dt_w, partA, zbuf,
                blockIdx.x * 4 + (threadIdx.x >> 6), threadIdx.x & 63);
}

__global__ __launch_bounds__(256) void kB(
    const float* __restrict__ x, const float* __restrict__ log_A,
    const float* __restrict__ dt_b, const float* __restrict__ ln_w,
    const float* __restrict__ ln_b, const float* __restrict__ dt_w,
    const float2* __restrict__ partA, const float* __restrict__ zbuf,
    float2* __restrict__ statbuf, float* __restrict__ abuf,
    float* __restrict__ Fbuf, float* __restrict__ Pbuf)
{
    phaseB_body(x, log_A, dt_b, ln_w, ln_b, dt_w, partA, zbuf,
                statbuf, abuf, Fbuf, Pbuf,
                blockIdx.x * 4 + (threadIdx.x >> 6), threadIdx.x & 63);
}

__global__ __launch_bounds__(256) void kC(
    const float* __restrict__ x, const float* __restrict__ ln_w,
    const float* __restrict__ ln_b,
    const float2* __restrict__ statbuf, const float* __restrict__ abuf,
    const float* __restrict__ Fbuf, const float* __restrict__ Pbuf,
    float* __restrict__ out)
{
    phaseC_body(x, ln_w, ln_b, statbuf, abuf, Fbuf, Pbuf, out,
                blockIdx.x * 4 + (threadIdx.x >> 6), threadIdx.x & 63);
}

extern "C" void kernel_launch(void* const* d_in, const int* in_sizes, int n_in,
                              void* d_out, int out_size, void* d_ws, size_t ws_size,
                              hipStream_t stream) {
    const float* x     = (const float*)d_in[0];
    const float* log_A = (const float*)d_in[1];
    const float* dt_w  = (const float*)d_in[2];
    const float* dt_b  = (const float*)d_in[3];
    const float* ln_w  = (const float*)d_in[4];
    const float* ln_b  = (const float*)d_in[5];
    float* out = (float*)d_out;

    char* ws = (char*)d_ws;
    float2* partA   = (float2*)(ws);                    //  32 KB  [BB*SS][4]
    float*  zbuf    = (float*)(ws + (64 << 10));        // 256 KB  [BB*SS][DD]
    float2* statbuf = (float2*)(ws + (320 << 10));      //   8 KB  [BB*SS]
    float*  abuf    = (float*)(ws + (384 << 10));       // 256 KB  [BB*SS][DD]
    float*  Fbuf    = (float*)(ws + (640 << 10));       //   1 MB  [4096][DD]
    float*  Pbuf    = (float*)(ws + (1664 << 10));      //  16 KB  [4096]

    void* args[] = {
        (void*)&x, (void*)&log_A, (void*)&dt_w, (void*)&dt_b,
        (void*)&ln_w, (void*)&ln_b, (void*)&out,
        (void*)&partA, (void*)&zbuf, (void*)&statbuf, (void*)&abuf,
        (void*)&Fbuf, (void*)&Pbuf
    };
    hipError_t err = hipLaunchCooperativeKernel((const void*)fused_all,
                                                dim3(BB * SS * 4 / 4), dim3(256),
                                                args, 0, stream);
    if (err != hipSuccess) {
        // deterministic fallback: identical phases as three plain dispatches
        kA<<<BB * SS, 256, 0, stream>>>(x, ln_w, dt_w, partA, zbuf);
        kB<<<BB * DD * NC / 4, 256, 0, stream>>>(x, log_A, dt_b, ln_w, ln_b, dt_w,
                                                 partA, zbuf, statbuf, abuf, Fbuf, Pbuf);
        kC<<<BB * DD * NC / 4, 256, 0, stream>>>(x, ln_w, ln_b, statbuf, abuf,
                                                 Fbuf, Pbuf, out);
    }
}

// Round 7
// 91.914 us; speedup vs baseline: 3.3649x; 3.3649x over previous
//
#include <hip/hip_runtime.h>
#include <math.h>

#define BB 2
#define SS 512
#define DD 64
#define DDDD 4096   // DD*DD
#define NC 32       // time chunks
#define CL (SS / NC) // 16 chunk length

// -------- Kernel 1: per (b,s) LayerNorm stats + dt + decay a = exp(dt * -exp(log_A)) --------
__global__ __launch_bounds__(256) void k1_stats(
    const float* __restrict__ x, const float* __restrict__ log_A,
    const float* __restrict__ dt_w, const float* __restrict__ dt_b,
    const float* __restrict__ ln_w, const float* __restrict__ ln_b,
    float* __restrict__ a_out, float2* __restrict__ stats)
{
    const int bs  = blockIdx.x;       // b*SS + s
    const int tid = threadIdx.x;      // 256 threads x 16 elems

    const float4* xp4 = (const float4*)(x + (size_t)bs * DDDD + tid * 16);
    float4 v0 = xp4[0], v1 = xp4[1], v2 = xp4[2], v3 = xp4[3];

    float sum = (v0.x+v0.y+v0.z+v0.w) + (v1.x+v1.y+v1.z+v1.w)
              + (v2.x+v2.y+v2.z+v2.w) + (v3.x+v3.y+v3.z+v3.w);
    float sq  = (v0.x*v0.x+v0.y*v0.y+v0.z*v0.z+v0.w*v0.w)
              + (v1.x*v1.x+v1.y*v1.y+v1.z*v1.z+v1.w*v1.w)
              + (v2.x*v2.x+v2.y*v2.y+v2.z*v2.z+v2.w*v2.w)
              + (v3.x*v3.x+v3.y*v3.y+v3.z*v3.z+v3.w*v3.w);

    #pragma unroll
    for (int off = 32; off > 0; off >>= 1) {
        sum += __shfl_down(sum, off);
        sq  += __shfl_down(sq,  off);
    }
    __shared__ float s_sum[4], s_sq[4];
    const int wv = tid >> 6, ln = tid & 63;
    if (ln == 0) { s_sum[wv] = sum; s_sq[wv] = sq; }
    __syncthreads();
    const float tsum = s_sum[0] + s_sum[1] + s_sum[2] + s_sum[3];
    const float tsq  = s_sq[0]  + s_sq[1]  + s_sq[2]  + s_sq[3];
    const float mu   = tsum * (1.0f / DDDD);
    const float var  = tsq  * (1.0f / DDDD) - mu * mu;
    const float rstd = rsqrtf(var + 1e-5f);

    const float4* lw4 = (const float4*)(ln_w + tid * 16);
    const float4* lb4 = (const float4*)(ln_b + tid * 16);
    const float4* dw4 = (const float4*)(dt_w + (tid & 3) * 16);
    float p = 0.f;
    #define ACC4(vv, ii) { \
        float4 lw = lw4[ii], lb = lb4[ii], dw = dw4[ii];            \
        p = fmaf(fmaf((vv.x - mu) * rstd, lw.x, lb.x), dw.x, p);    \
        p = fmaf(fmaf((vv.y - mu) * rstd, lw.y, lb.y), dw.y, p);    \
        p = fmaf(fmaf((vv.z - mu) * rstd, lw.z, lb.z), dw.z, p);    \
        p = fmaf(fmaf((vv.w - mu) * rstd, lw.w, lb.w), dw.w, p);    \
    }
    ACC4(v0, 0); ACC4(v1, 1); ACC4(v2, 2); ACC4(v3, 3);
    #undef ACC4

    p += __shfl_xor(p, 1);
    p += __shfl_xor(p, 2);

    if ((tid & 3) == 0) {
        const int d = tid >> 2;
        float z = p + dt_b[0];
        float dt = (z > 20.f) ? z : log1pf(expf(z));   // softplus
        float la = dt * (-expf(log_A[d]));             // <= 0 always
        a_out[bs * DD + d] = expf(la);                 // decay in (0,1]
    }
    if (tid == 0) stats[bs] = make_float2(mu, rstd);
}

// -------- Kernel 2a: per (b,r,chunk) local scan -> (F[c], P) --------
__global__ __launch_bounds__(256) void k2a_partial(
    const float* __restrict__ x, const float* __restrict__ a_in,
    const float* __restrict__ ln_w, const float* __restrict__ ln_b,
    const float2* __restrict__ stats,
    float* __restrict__ Fbuf, float* __restrict__ Pbuf)
{
    const int gw = blockIdx.x * 4 + (threadIdx.x >> 6);   // 0..BB*DD*NC-1
    const int c  = threadIdx.x & 63;
    const int ch = gw & (NC - 1);
    const int br = gw >> 5;                               // log2(NC)=5
    const int b  = br >> 6, r = br & 63;

    const float lnw = ln_w[r * DD + c];
    const float lnb = ln_b[r * DD + c];

    const int t0 = ch * CL;
    const float*  xp = x + (((size_t)(b * SS + t0)) * DD + r) * DD + c;
    const float*  ap = a_in + (b * SS + t0) * DD + r;
    const float2* sp = stats + b * SS + t0;

    float state = 0.f, P = 1.f;
    #pragma unroll
    for (int t = 0; t < CL; t += 8) {
        float xv[8], av[8]; float2 st[8];
        #pragma unroll
        for (int i = 0; i < 8; ++i) {
            xv[i] = xp[(size_t)(t + i) * DDDD];
            av[i] = ap[(t + i) * DD];
            st[i] = sp[t + i];
        }
        #pragma unroll
        for (int i = 0; i < 8; ++i) {
            float xn = fmaf((xv[i] - st[i].x) * st[i].y, lnw, lnb);
            state = fmaf(av[i], state, xn);
            P *= av[i];
        }
    }
    Fbuf[(size_t)gw * DD + c] = state;
    if (c == 0) Pbuf[gw] = P;
}

// -------- Kernel 2b: carry from all earlier chunks, rescan, write out --------
__global__ __launch_bounds__(256) void k2b_final(
    const float* __restrict__ x, const float* __restrict__ a_in,
    const float* __restrict__ ln_w, const float* __restrict__ ln_b,
    const float2* __restrict__ stats,
    const float* __restrict__ Fbuf, const float* __restrict__ Pbuf,
    float* __restrict__ out)
{
    const int gw = blockIdx.x * 4 + (threadIdx.x >> 6);
    const int c  = threadIdx.x & 63;
    const int ch = gw & (NC - 1);
    const int br = gw >> 5;
    const int b  = br >> 6, r = br & 63;

    // ---- carry first: issue all F/P loads up front, masked FMA chain ----
    float carry = 0.f;
    {
        float f[NC], p[NC];
        #pragma unroll
        for (int v = 0; v < NC; ++v) {
            f[v] = Fbuf[(size_t)(br * NC + v) * DD + c];
            p[v] = Pbuf[br * NC + v];
        }
        #pragma unroll
        for (int v = 0; v < NC; ++v) {
            float pv = (v < ch) ? p[v] : 1.f;
            float fv = (v < ch) ? f[v] : 0.f;
            carry = fmaf(pv, carry, fv);
        }
    }

    const float lnw = ln_w[r * DD + c];
    const float lnb = ln_b[r * DD + c];

    const int t0 = ch * CL;
    const size_t xoff = (((size_t)(b * SS + t0)) * DD + r) * DD + c;
    const float*  xp = x + xoff;
    const float*  ap = a_in + (b * SS + t0) * DD + r;
    const float2* sp = stats + b * SS + t0;
    float* op = out + xoff;

    float state = carry;
    #pragma unroll
    for (int t = 0; t < CL; t += 8) {
        float xv[8], av[8]; float2 st[8];
        #pragma unroll
        for (int i = 0; i < 8; ++i) {
            xv[i] = xp[(size_t)(t + i) * DDDD];
            av[i] = ap[(t + i) * DD];
            st[i] = sp[t + i];
        }
        #pragma unroll
        for (int i = 0; i < 8; ++i) {
            float xn = fmaf((xv[i] - st[i].x) * st[i].y, lnw, lnb);
            state = fmaf(av[i], state, xn);
            op[(size_t)(t + i) * DDDD] = state + xv[i];
        }
    }
}

extern "C" void kernel_launch(void* const* d_in, const int* in_sizes, int n_in,
                              void* d_out, int out_size, void* d_ws, size_t ws_size,
                              hipStream_t stream) {
    const float* x     = (const float*)d_in[0];
    const float* log_A = (const float*)d_in[1];
    const float* dt_w  = (const float*)d_in[2];
    const float* dt_b  = (const float*)d_in[3];
    const float* ln_w  = (const float*)d_in[4];
    const float* ln_b  = (const float*)d_in[5];
    float* out = (float*)d_out;

    char* ws = (char*)d_ws;
    float*  a_buf = (float*)ws;                            // B*S*D floats   (256 KB)
    float2* stats = (float2*)(ws + 262144);                // B*S float2     (8 KB)
    float*  Fbuf  = (float*)(ws + 262144 + 8192);          // 4096*64 floats (1 MB)
    float*  Pbuf  = (float*)(ws + 262144 + 8192 + 1048576);// 4096 floats    (16 KB)

    k1_stats<<<BB * SS, 256, 0, stream>>>(x, log_A, dt_w, dt_b, ln_w, ln_b, a_buf, stats);
    k2a_partial<<<BB * DD * NC / 4, 256, 0, stream>>>(x, a_buf, ln_w, ln_b, stats, Fbuf, Pbuf);
    k2b_final<<<BB * DD * NC / 4, 256, 0, stream>>>(x, a_buf, ln_w, ln_b, stats, Fbuf, Pbuf, out);
}